// Round 4
// baseline (141.174 us; speedup 1.0000x reference)
//
#include <hip/hip_runtime.h>

#define B_ 8
#define P_ 65536
#define G_ 32
#define C_ 2
#define K_ 5
#define T1_ 0.35f
#define T2_ 0.5f
#define ALPHA_ 0.25f
#define BETA_ 0.11f
#define V0_ 0.1f
#define V1_ 0.2f

#define NBLK_ 256           // kB-part blocks per image (P_/256)
#define CH_ 8               // top-5 chunks per (b,g)
#define CHP_ (P_ / CH_)     // 8192 anchors per chunk

// ws layout:
//   [0)        Hdr (2 KB, memset to 0 each call)
//   [8192)     float best_score[B_*P_]   (2 MB)
//   +2MB       int   best_idx[B_*P_]     (2 MB)
//   +2MB       double fl_n_p[2048]; double sl_n_p[2048]   (32 KB)
//   +32KB      float cv5[B_*G_*CH_*5]; int ci5[B_*G_*CH_*5]  (80 KB)
struct Hdr { int match_cnt[B_ * G_]; int c_match[B_ * G_]; };

// ---------------- numerics helpers (contract off => deterministic across call sites) ----
struct DecBox { float x1, y1, x2, y2, area; };

__device__ __forceinline__ DecBox decode_box(float4 pr, float4 lc) {
#pragma clang fp contract(off)
    DecBox d;
    float dcx = pr.x + lc.x * V0_ * pr.z;
    float dcy = pr.y + lc.y * V0_ * pr.w;
    float dw = pr.z * expf(lc.z * V1_);
    float dh = pr.w * expf(lc.w * V1_);
    d.x1 = dcx - dw * 0.5f; d.y1 = dcy - dh * 0.5f;
    d.x2 = dcx + dw * 0.5f; d.y2 = dcy + dh * 0.5f;
    d.area = (d.x2 - d.x1) * (d.y2 - d.y1);
    return d;
}

__device__ __forceinline__ float iou_dec(DecBox d, float tx1, float ty1, float tx2, float ty2) {
#pragma clang fp contract(off)
    float lx = fmaxf(tx1, d.x1), ly = fmaxf(ty1, d.y1);
    float rx = fminf(tx2, d.x2), ry = fminf(ty2, d.y2);
    float w = fmaxf(rx - lx, 0.f), hh = fmaxf(ry - ly, 0.f);
    float inter = w * hh;
    float aa = (tx2 - tx1) * (ty2 - ty1);
    return inter / (aa + d.area - inter);
}

__device__ __forceinline__ float iou_corner(float ax1, float ay1, float ax2, float ay2,
                                            float bx1, float by1, float bx2, float by2) {
    float lx = fmaxf(ax1, bx1), ly = fmaxf(ay1, by1);
    float rx = fminf(ax2, bx2), ry = fminf(ay2, by2);
    float w = fmaxf(rx - lx, 0.f), hh = fmaxf(ry - ly, 0.f);
    float inter = w * hh;
    float aa = (ax2 - ax1) * (ay2 - ay1);
    float ab = (bx2 - bx1) * (by2 - by1);
    return inter / (aa + ab - inter);
}

__device__ __forceinline__ float focal_f(float t, float x, float fiou) {
    float ce = fmaxf(x, 0.f) - x * t + log1pf(expf(-fabsf(x)));
    float a = (t * ALPHA_ + (1.f - t) * (1.f - ALPHA_)) * fiou;
    float pt = (t == 1.0f) ? x : 1.f - x;
    float om = 1.f - pt;
    return a * om * om * ce;  // GAMMA = 2
}

__device__ __forceinline__ float sml1(float p, float t) {
    float x = fabsf(p - t);
    return (x >= BETA_) ? (x - 0.5f * BETA_) : (0.5f * x * x / BETA_);
}

// top-5 by (value desc, index asc) — the stable-argsort order
__device__ __forceinline__ void top5_insert(float v, int i, float lv[5], int li[5]) {
    if ((v > lv[4]) || (v == lv[4] && i < li[4])) {
        lv[4] = v; li[4] = i;
#pragma unroll
        for (int k = 4; k > 0; --k) {
            bool sw = (lv[k] > lv[k - 1]) || (lv[k] == lv[k - 1] && li[k] < li[k - 1]);
            if (sw) {
                float tv = lv[k]; lv[k] = lv[k - 1]; lv[k - 1] = tv;
                int ti = li[k]; li[k] = li[k - 1]; li[k - 1] = ti;
            }
        }
    }
}

// ---------------- kA: prior<->gt IoU, best match per anchor, match_cnt ----------------
__global__ __launch_bounds__(256) void kA(const float* __restrict__ priors,
                                          const float* __restrict__ targets, Hdr* h,
                                          float* __restrict__ best_score,
                                          int* __restrict__ best_idx) {
    int tid = threadIdx.x;
    int p = blockIdx.x * 256 + tid, b = blockIdx.y;
    __shared__ float tr[G_ * 5];
    __shared__ int hist[G_];
    if (tid < G_ * 5) tr[tid] = targets[b * G_ * 5 + tid];
    if (tid < G_) hist[tid] = 0;
    __syncthreads();
    float4 pr = ((const float4*)priors)[p];
    float px1 = pr.x - pr.z * 0.5f, py1 = pr.y - pr.w * 0.5f;
    float px2 = pr.x + pr.z * 0.5f, py2 = pr.y + pr.w * 0.5f;
    float best = -INFINITY;
    int bi = 0;
    for (int g = 0; g < G_; ++g) {
        float v = iou_corner(tr[g * 5], tr[g * 5 + 1], tr[g * 5 + 2], tr[g * 5 + 3],
                             px1, py1, px2, py2);
        if (v > best) { best = v; bi = g; }  // first-max == jnp.argmax
    }
    best_score[b * P_ + p] = best;
    best_idx[b * P_ + p] = bi;
    if (best > T1_) atomicAdd(&hist[bi], 1);
    __syncthreads();
    if (tid < G_ && hist[tid]) atomicAdd(&h->match_cnt[b * G_ + tid], hist[tid]);
}

// ---------------- kBD: fused launch. blocks x<NBLK_: normal-loss pass; else chunked top-5 ----
__global__ __launch_bounds__(256) void kBD(
    const float* __restrict__ loc, const float* __restrict__ conf,
    const float* __restrict__ priors, const float* __restrict__ targets,
    Hdr* __restrict__ h,
    const float* __restrict__ best_score, const int* __restrict__ best_idx,
    double* __restrict__ fl_n_p, double* __restrict__ sl_n_p,
    float* __restrict__ cv5, int* __restrict__ ci5) {
    int tid = threadIdx.x, b = blockIdx.y;
    __shared__ union USm {
        struct { float tr[G_ * 5]; int outf[G_]; int hist[G_]; double wred[8]; } Bp;
        struct { float sv[256 * 5]; int si[256 * 5]; } Dp;
    } sm;

    if (blockIdx.x < NBLK_) {
        // ---------- kB part: cmax/ignore, masked argmax -> c_match, focal+smoothL1 sums ----
        int p = blockIdx.x * 256 + tid;
        if (tid < G_ * 5) sm.Bp.tr[tid] = targets[b * G_ * 5 + tid];
        if (tid < G_) {
            sm.Bp.hist[tid] = 0;
            sm.Bp.outf[tid] = (h->match_cnt[b * G_ + tid] < K_) ? 1 : 0;
        }
        __syncthreads();
        float4 pr = ((const float4*)priors)[p];
        float4 lc = ((const float4*)loc)[(size_t)b * P_ + p];
        float bs = best_score[b * P_ + p];
        int bi = best_idx[b * P_ + p];
        DecBox d = decode_box(pr, lc);
        float cmax = -INFINITY, mbest = -INFINITY;
        int mg = 0;
        for (int g = 0; g < G_; ++g) {
            float v = iou_dec(d, sm.Bp.tr[g * 5], sm.Bp.tr[g * 5 + 1],
                              sm.Bp.tr[g * 5 + 2], sm.Bp.tr[g * 5 + 3]);
            cmax = fmaxf(cmax, v);
            bool kill = sm.Bp.outf[g] && (bi == g) && (bs > T1_);
            float v2 = kill ? 0.f : v;
            float m = sm.Bp.outf[g] ? v2 : -1.f;
            if (m > mbest) { mbest = m; mg = g; }  // first-max
        }
        if (mbest > T2_) atomicAdd(&sm.Bp.hist[mg], 1);
        bool n_pos = bs > T1_;
        bool ignore = (cmax > T2_) && (bs < T1_);
        bool neg = !(n_pos || ignore);
        double fl = 0.0, sl = 0.0;
        int lab = (int)sm.Bp.tr[bi * 5 + 4];
        float2 cf = ((const float2*)conf)[(size_t)b * P_ + p];
        float cfs[2] = {cf.x, cf.y};
#pragma unroll
        for (int c = 0; c < C_; ++c) {
            if (n_pos) fl += (double)focal_f((c == lab) ? 1.f : 0.f, cfs[c], 1.f);
            else if (neg) fl += (double)focal_f(0.f, cfs[c], 1.f);
        }
        if (n_pos) {
            float tx1 = sm.Bp.tr[bi * 5], ty1 = sm.Bp.tr[bi * 5 + 1];
            float tx2 = sm.Bp.tr[bi * 5 + 2], ty2 = sm.Bp.tr[bi * 5 + 3];
            float e0 = ((tx1 + tx2) * 0.5f - pr.x) / (V0_ * pr.z);
            float e1 = ((ty1 + ty2) * 0.5f - pr.y) / (V0_ * pr.w);
            float e2 = logf((tx2 - tx1) / pr.z) / V1_;
            float e3 = logf((ty2 - ty1) / pr.w) / V1_;
            sl = (double)sml1(lc.x, e0) + (double)sml1(lc.y, e1) +
                 (double)sml1(lc.z, e2) + (double)sml1(lc.w, e3);
        }
        int lane = tid & 63, w = tid >> 6;
        for (int off = 32; off > 0; off >>= 1) {
            fl += __shfl_down(fl, off, 64);
            sl += __shfl_down(sl, off, 64);
        }
        if (lane == 0) { sm.Bp.wred[w] = fl; sm.Bp.wred[4 + w] = sl; }
        __syncthreads();
        if (tid == 0)
            fl_n_p[b * NBLK_ + blockIdx.x] =
                sm.Bp.wred[0] + sm.Bp.wred[1] + sm.Bp.wred[2] + sm.Bp.wred[3];
        if (tid == 1)
            sl_n_p[b * NBLK_ + blockIdx.x] =
                sm.Bp.wred[4] + sm.Bp.wred[5] + sm.Bp.wred[6] + sm.Bp.wred[7];
        if (tid < G_ && sm.Bp.hist[tid]) atomicAdd(&h->c_match[b * G_ + tid], sm.Bp.hist[tid]);
    } else {
        // ---------- kD part: chunked top-5 of c_iou2 row (b,g), chunk ch ----
        int t2 = blockIdx.x - NBLK_;
        int g = t2 >> 3, ch = t2 & (CH_ - 1);
        float tx1 = targets[(b * G_ + g) * 5 + 0], ty1 = targets[(b * G_ + g) * 5 + 1];
        float tx2 = targets[(b * G_ + g) * 5 + 2], ty2 = targets[(b * G_ + g) * 5 + 3];
        int outfg = (h->match_cnt[b * G_ + g] < K_) ? 1 : 0;
        float lv[5];
        int li[5];
#pragma unroll
        for (int k = 0; k < 5; ++k) { lv[k] = -INFINITY; li[k] = 0x7fffffff; }
        int base = ch * CHP_;
        for (int it = 0; it < CHP_ / 256; ++it) {
            int p = base + it * 256 + tid;
            int bi = best_idx[b * P_ + p];
            float bs = best_score[b * P_ + p];
            float v2;
            if (outfg && bi == g && bs > T1_) v2 = 0.f;  // kill
            else {
                float4 pr = ((const float4*)priors)[p];
                float4 lc = ((const float4*)loc)[(size_t)b * P_ + p];
                v2 = iou_dec(decode_box(pr, lc), tx1, ty1, tx2, ty2);
            }
            top5_insert(v2, p, lv, li);
        }
#pragma unroll
        for (int k = 0; k < 5; ++k) { sm.Dp.sv[tid * 5 + k] = lv[k]; sm.Dp.si[tid * 5 + k] = li[k]; }
        __syncthreads();
        for (int str = 128; str > 0; str >>= 1) {
            if (tid < str) {
                int a = 0, c = 0;
                float ov[5];
                int oi[5];
#pragma unroll
                for (int k = 0; k < 5; ++k) {
                    float va = sm.Dp.sv[tid * 5 + a], vb = sm.Dp.sv[(tid + str) * 5 + c];
                    int ia = sm.Dp.si[tid * 5 + a], ib = sm.Dp.si[(tid + str) * 5 + c];
                    bool ta = (va > vb) || (va == vb && ia < ib);
                    ov[k] = ta ? va : vb;
                    oi[k] = ta ? ia : ib;
                    if (ta) a++; else c++;
                }
#pragma unroll
                for (int k = 0; k < 5; ++k) { sm.Dp.sv[tid * 5 + k] = ov[k]; sm.Dp.si[tid * 5 + k] = oi[k]; }
            }
            __syncthreads();
        }
        if (tid == 0) {
#pragma unroll
            for (int k = 0; k < 5; ++k) {
                cv5[((b * G_ + g) * CH_ + ch) * 5 + k] = sm.Dp.sv[k];
                ci5[((b * G_ + g) * CH_ + ch) * 5 + k] = sm.Dp.si[k];
            }
        }
    }
}

// ---------------- kTail: everything downstream, 1 block, thread t = (b,g) --------------
__global__ __launch_bounds__(256) void kTail(
    const float* __restrict__ loc, const float* __restrict__ conf,
    const float* __restrict__ priors, const float* __restrict__ targets,
    const Hdr* __restrict__ h,
    const double* __restrict__ fl_n_p, const double* __restrict__ sl_n_p,
    const float* __restrict__ cv5, const int* __restrict__ ci5,
    float* __restrict__ out) {
    int t = threadIdx.x, b = t >> 5, g = t & 31;
    __shared__ int selp[256][5];
    __shared__ float selv[256][5];
    __shared__ int nS[256];
    __shared__ double aFlc[B_], aSlc[B_], aFln[B_], aSln[B_];
    __shared__ int aNp[B_], aCs[B_], aNpc[B_];

    int mc = h->match_cnt[t];
    int cm = h->c_match[t];
    int n = (mc < K_) ? min(cm, K_ - mc) : 0;
    nS[t] = n;

    // merge 8 chunk top-5 lists -> global top-5 for (b,g)
    float mv[5];
    int mi[5];
#pragma unroll
    for (int k = 0; k < 5; ++k) { mv[k] = -INFINITY; mi[k] = 0x7fffffff; }
    for (int ch = 0; ch < CH_; ++ch)
#pragma unroll
        for (int k = 0; k < 5; ++k)
            top5_insert(cv5[(t * CH_ + ch) * 5 + k], ci5[(t * CH_ + ch) * 5 + k], mv, mi);
#pragma unroll
    for (int k = 0; k < 5; ++k) {
        selp[t][k] = (k < n) ? mi[k] : -1;
        selv[t][k] = mv[k];
    }
    __syncthreads();

    // override resolution (scan over g ascending: later g wins) + comp losses
    double flc = 0.0, slc = 0.0;
    int alive = 0;
    float tg0 = targets[t * 5 + 0], tg1 = targets[t * 5 + 1];
    float tg2 = targets[t * 5 + 2], tg3 = targets[t * 5 + 3];
    float labf = targets[t * 5 + 4];
    int labi = (int)labf;
    for (int k = 0; k < n; ++k) {
        int p = mi[k];
        bool dead = false;
        for (int g2 = g + 1; g2 < G_; ++g2) {
            int q = b * G_ + g2;
            int n2 = nS[q];
            for (int k2 = 0; k2 < n2; ++k2)
                if (selp[q][k2] == p) dead = true;
        }
        if (!dead) {
            alive++;
            float4 pr = ((const float4*)priors)[p];
            float4 lc = ((const float4*)loc)[(size_t)b * P_ + p];
            float e0 = ((tg0 + tg2) * 0.5f - pr.x) / (V0_ * pr.z);
            float e1 = ((tg1 + tg3) * 0.5f - pr.y) / (V0_ * pr.w);
            float e2 = logf((tg2 - tg0) / pr.z) / V1_;
            float e3 = logf((tg3 - tg1) / pr.w) / V1_;
            slc += (double)sml1(lc.x, e0) + (double)sml1(lc.y, e1) +
                   (double)sml1(lc.z, e2) + (double)sml1(lc.w, e3);
            float2 cf = ((const float2*)conf)[(size_t)b * P_ + p];
            float cfs[2] = {cf.x, cf.y};
#pragma unroll
            for (int c = 0; c < C_; ++c) {
                float tt = (c == labi) ? labf : 0.f;  // labels[g] * one_hot
                flc += (double)focal_f(tt, cfs[c], mv[k]);
            }
        }
    }

    // per-b reductions within 32-thread subgroups (in-wave, no barriers)
    int rmc = mc, rn = n, ra = alive;
    double rf = flc, rs = slc;
    double pf = 0.0, ps = 0.0;  // normal-loss partials: slots [t*8, t*8+8) all belong to b
    for (int j = 0; j < 8; ++j) { pf += fl_n_p[t * 8 + j]; ps += sl_n_p[t * 8 + j]; }
    for (int off = 16; off > 0; off >>= 1) {
        rmc += __shfl_down(rmc, off, 32);
        rn += __shfl_down(rn, off, 32);
        ra += __shfl_down(ra, off, 32);
        rf += __shfl_down(rf, off, 32);
        rs += __shfl_down(rs, off, 32);
        pf += __shfl_down(pf, off, 32);
        ps += __shfl_down(ps, off, 32);
    }
    if (g == 0) {
        aNp[b] = rmc; aCs[b] = rn; aNpc[b] = ra;
        aFlc[b] = rf; aSlc[b] = rs; aFln[b] = pf; aSln[b] = ps;
    }
    __syncthreads();
    if (t == 0) {
        double sll = 0.0, scl = 0.0;
        for (int b2 = 0; b2 < B_; ++b2) {
            double l_loc = 0.0, l_cls = 0.0;
            int npos = aNp[b2];
            if (npos > 0) {
                l_cls += aFln[b2] / (double)npos;
                l_loc += aSln[b2] / (double)npos;
            }
            int csum = aCs[b2];
            if (csum > 0) {
                int npc = (aNpc[b2] > 1) ? aNpc[b2] : 1;
                l_loc += aSlc[b2] / (double)npc;
                l_cls += aFlc[b2] / (double)csum;
            }
            sll += l_loc;
            scl += l_cls;
        }
        out[0] = (float)(sll / B_);
        out[1] = (float)(scl / B_);
    }
}

extern "C" void kernel_launch(void* const* d_in, const int* in_sizes, int n_in,
                              void* d_out, int out_size, void* d_ws, size_t ws_size,
                              hipStream_t stream) {
    (void)in_sizes; (void)n_in; (void)out_size; (void)ws_size;
    const float* loc = (const float*)d_in[0];
    const float* conf = (const float*)d_in[1];
    const float* priors = (const float*)d_in[2];
    const float* targets = (const float*)d_in[3];
    float* out = (float*)d_out;
    char* ws = (char*)d_ws;
    Hdr* h = (Hdr*)ws;
    float* best_score = (float*)(ws + 8192);
    int* best_idx = (int*)(ws + 8192 + (size_t)B_ * P_ * 4);
    double* fl_n_p = (double*)(ws + 8192 + (size_t)B_ * P_ * 8);
    double* sl_n_p = fl_n_p + B_ * NBLK_;
    float* cv5 = (float*)(sl_n_p + B_ * NBLK_);
    int* ci5 = (int*)(cv5 + B_ * G_ * CH_ * 5);

    hipMemsetAsync(h, 0, sizeof(Hdr), stream);
    kA<<<dim3(NBLK_, B_), 256, 0, stream>>>(priors, targets, h, best_score, best_idx);
    kBD<<<dim3(NBLK_ + G_ * CH_, B_), 256, 0, stream>>>(loc, conf, priors, targets, h,
                                                        best_score, best_idx, fl_n_p, sl_n_p,
                                                        cv5, ci5);
    kTail<<<1, 256, 0, stream>>>(loc, conf, priors, targets, h, fl_n_p, sl_n_p, cv5, ci5, out);
}

// Round 5
// 56.911 us; speedup vs baseline: 2.4806x; 2.4806x over previous
//
#include <hip/hip_runtime.h>

#define B_ 8
#define P_ 65536
#define G_ 32
#define C_ 2
#define K_ 5
#define T1_ 0.35f
#define T2_ 0.5f
#define ALPHA_ 0.25f
#define BETA_ 0.11f
#define V0_ 0.1f
#define V1_ 0.2f

#define NBLK_ 256           // kB blocks per image (P_/256)
#define CH_ 8               // top-5 chunks per (b,g)
#define CHP_ (P_ / CH_)     // 8192 anchors per chunk

// ws layout:
//   [0)        Hdr (2 KB, memset to 0 each call)
//   [8192)     float best_score[B_*P_]   (2 MB)
//   +2MB       int   best_idx[B_*P_]     (2 MB)
//   +2MB       double fl_n_p[2048]; double sl_n_p[2048]   (32 KB)
//   +32KB      float cv5[B_*G_*CH_*5]; int ci5[B_*G_*CH_*5]  (80 KB)
struct Hdr { int match_cnt[B_ * G_]; int c_match[B_ * G_]; };

// ---------------- numerics helpers (contract off => deterministic across call sites) ----
struct DecBox { float x1, y1, x2, y2, area; };

__device__ __forceinline__ DecBox decode_box(float4 pr, float4 lc) {
#pragma clang fp contract(off)
    DecBox d;
    float dcx = pr.x + lc.x * V0_ * pr.z;
    float dcy = pr.y + lc.y * V0_ * pr.w;
    float dw = pr.z * expf(lc.z * V1_);
    float dh = pr.w * expf(lc.w * V1_);
    d.x1 = dcx - dw * 0.5f; d.y1 = dcy - dh * 0.5f;
    d.x2 = dcx + dw * 0.5f; d.y2 = dcy + dh * 0.5f;
    d.area = (d.x2 - d.x1) * (d.y2 - d.y1);
    return d;
}

// aa = precomputed gt area
__device__ __forceinline__ float iou_dec(DecBox d, float aa,
                                         float tx1, float ty1, float tx2, float ty2) {
#pragma clang fp contract(off)
    float lx = fmaxf(tx1, d.x1), ly = fmaxf(ty1, d.y1);
    float rx = fminf(tx2, d.x2), ry = fminf(ty2, d.y2);
    float w = fmaxf(rx - lx, 0.f), hh = fmaxf(ry - ly, 0.f);
    float inter = w * hh;
    return inter / (aa + d.area - inter);
}

__device__ __forceinline__ float iou_corner(float ax1, float ay1, float ax2, float ay2,
                                            float bx1, float by1, float bx2, float by2) {
    float lx = fmaxf(ax1, bx1), ly = fmaxf(ay1, by1);
    float rx = fminf(ax2, bx2), ry = fminf(ay2, by2);
    float w = fmaxf(rx - lx, 0.f), hh = fmaxf(ry - ly, 0.f);
    float inter = w * hh;
    float aa = (ax2 - ax1) * (ay2 - ay1);
    float ab = (bx2 - bx1) * (by2 - by1);
    return inter / (aa + ab - inter);
}

__device__ __forceinline__ float focal_f(float t, float x, float fiou) {
    float ce = fmaxf(x, 0.f) - x * t + log1pf(expf(-fabsf(x)));
    float a = (t * ALPHA_ + (1.f - t) * (1.f - ALPHA_)) * fiou;
    float pt = (t == 1.0f) ? x : 1.f - x;
    float om = 1.f - pt;
    return a * om * om * ce;  // GAMMA = 2
}

__device__ __forceinline__ float sml1(float p, float t) {
    float x = fabsf(p - t);
    return (x >= BETA_) ? (x - 0.5f * BETA_) : (0.5f * x * x / BETA_);
}

// top-5 by (value desc, index asc) — the stable-argsort order
__device__ __forceinline__ void top5_insert(float v, int i, float lv[5], int li[5]) {
    if ((v > lv[4]) || (v == lv[4] && i < li[4])) {
        lv[4] = v; li[4] = i;
#pragma unroll
        for (int k = 4; k > 0; --k) {
            bool sw = (lv[k] > lv[k - 1]) || (lv[k] == lv[k - 1] && li[k] < li[k - 1]);
            if (sw) {
                float tv = lv[k]; lv[k] = lv[k - 1]; lv[k - 1] = tv;
                int ti = li[k]; li[k] = li[k - 1]; li[k - 1] = ti;
            }
        }
    }
}

// ---------------- kA: prior<->gt IoU, best match per anchor, match_cnt ----------------
__global__ __launch_bounds__(256) void kA(const float* __restrict__ priors,
                                          const float* __restrict__ targets, Hdr* h,
                                          float* __restrict__ best_score,
                                          int* __restrict__ best_idx) {
    int tid = threadIdx.x;
    int p = blockIdx.x * 256 + tid, b = blockIdx.y;
    __shared__ float tr[G_ * 5];
    __shared__ int hist[G_];
    if (tid < G_ * 5) tr[tid] = targets[b * G_ * 5 + tid];
    if (tid < G_) hist[tid] = 0;
    __syncthreads();
    float4 pr = ((const float4*)priors)[p];
    float px1 = pr.x - pr.z * 0.5f, py1 = pr.y - pr.w * 0.5f;
    float px2 = pr.x + pr.z * 0.5f, py2 = pr.y + pr.w * 0.5f;
    float best = -INFINITY;
    int bi = 0;
    for (int g = 0; g < G_; ++g) {
        float v = iou_corner(tr[g * 5], tr[g * 5 + 1], tr[g * 5 + 2], tr[g * 5 + 3],
                             px1, py1, px2, py2);
        if (v > best) { best = v; bi = g; }  // first-max == jnp.argmax
    }
    best_score[b * P_ + p] = best;
    best_idx[b * P_ + p] = bi;
    if (best > T1_) atomicAdd(&hist[bi], 1);
    __syncthreads();
    if (tid < G_ && hist[tid]) atomicAdd(&h->match_cnt[b * G_ + tid], hist[tid]);
}

// ---------------- kB: normal losses + c_match (decode hoisted out of g-loop) ----------
__global__ __launch_bounds__(256) void kB(
    const float* __restrict__ loc, const float* __restrict__ conf,
    const float* __restrict__ priors, const float* __restrict__ targets,
    Hdr* __restrict__ h,
    const float* __restrict__ best_score, const int* __restrict__ best_idx,
    double* __restrict__ fl_n_p, double* __restrict__ sl_n_p) {
    int tid = threadIdx.x, b = blockIdx.y;
    int p = blockIdx.x * 256 + tid;
    __shared__ float tr[G_ * 5];
    __shared__ float sArea[G_];
    __shared__ int outf[G_];
    __shared__ int hist[G_];
    __shared__ double wred[8];
    if (tid < G_ * 5) tr[tid] = targets[b * G_ * 5 + tid];
    if (tid < G_) {
        const float* tg = targets + (b * G_ + tid) * 5;
        sArea[tid] = (tg[2] - tg[0]) * (tg[3] - tg[1]);
        hist[tid] = 0;
        outf[tid] = (h->match_cnt[b * G_ + tid] < K_) ? 1 : 0;
    }
    __syncthreads();
    float4 pr = ((const float4*)priors)[p];
    float4 lc = ((const float4*)loc)[(size_t)b * P_ + p];
    float bs = best_score[b * P_ + p];
    int bi = best_idx[b * P_ + p];
    DecBox d = decode_box(pr, lc);
    bool n_pos = bs > T1_;
    float cmax = -INFINITY, mbest = -INFINITY;
    int mg = 0;
    for (int g = 0; g < G_; ++g) {
        float v = iou_dec(d, sArea[g], tr[g * 5], tr[g * 5 + 1],
                          tr[g * 5 + 2], tr[g * 5 + 3]);
        cmax = fmaxf(cmax, v);
        bool kill = outf[g] && (bi == g) && n_pos;
        float v2 = kill ? 0.f : v;
        float m = outf[g] ? v2 : -1.f;
        if (m > mbest) { mbest = m; mg = g; }  // first-max
    }
    if (mbest > T2_) atomicAdd(&hist[mg], 1);
    bool ignore = (cmax > T2_) && (bs < T1_);
    bool neg = !(n_pos || ignore);
    double fl = 0.0, sl = 0.0;
    int lab = (int)tr[bi * 5 + 4];
    float2 cf = ((const float2*)conf)[(size_t)b * P_ + p];
    float cfs[2] = {cf.x, cf.y};
#pragma unroll
    for (int c = 0; c < C_; ++c) {
        if (n_pos) fl += (double)focal_f((c == lab) ? 1.f : 0.f, cfs[c], 1.f);
        else if (neg) fl += (double)focal_f(0.f, cfs[c], 1.f);
    }
    if (n_pos) {
        float tx1 = tr[bi * 5], ty1 = tr[bi * 5 + 1];
        float tx2 = tr[bi * 5 + 2], ty2 = tr[bi * 5 + 3];
        float e0 = ((tx1 + tx2) * 0.5f - pr.x) / (V0_ * pr.z);
        float e1 = ((ty1 + ty2) * 0.5f - pr.y) / (V0_ * pr.w);
        float e2 = logf((tx2 - tx1) / pr.z) / V1_;
        float e3 = logf((ty2 - ty1) / pr.w) / V1_;
        sl = (double)sml1(lc.x, e0) + (double)sml1(lc.y, e1) +
             (double)sml1(lc.z, e2) + (double)sml1(lc.w, e3);
    }
    int lane = tid & 63, w = tid >> 6;
    for (int off = 32; off > 0; off >>= 1) {
        fl += __shfl_down(fl, off, 64);
        sl += __shfl_down(sl, off, 64);
    }
    if (lane == 0) { wred[w] = fl; wred[4 + w] = sl; }
    __syncthreads();
    if (tid == 0)
        fl_n_p[b * NBLK_ + blockIdx.x] = wred[0] + wred[1] + wred[2] + wred[3];
    if (tid == 1)
        sl_n_p[b * NBLK_ + blockIdx.x] = wred[4] + wred[5] + wred[6] + wred[7];
    if (tid < G_ && hist[tid]) atomicAdd(&h->c_match[b * G_ + tid], hist[tid]);
}

// ---------------- kD: chunked top-5 of c_iou2 row (b,g) — ONLY for rows needing comp ---
__global__ __launch_bounds__(256) void kD(
    const float* __restrict__ loc, const float* __restrict__ priors,
    const float* __restrict__ targets, const Hdr* __restrict__ h,
    const float* __restrict__ best_score, const int* __restrict__ best_idx,
    float* __restrict__ cv5, int* __restrict__ ci5) {
    int tid = threadIdx.x, b = blockIdx.y;
    int g = blockIdx.x >> 3, ch = blockIdx.x & (CH_ - 1);
    int mc = h->match_cnt[b * G_ + g];
    int cm = h->c_match[b * G_ + g];
    int n = (mc < K_) ? min(cm, K_ - mc) : 0;
    if (n <= 0) return;  // uniform per block — the sparsity filter (most rows exit here)
    float tx1 = targets[(b * G_ + g) * 5 + 0], ty1 = targets[(b * G_ + g) * 5 + 1];
    float tx2 = targets[(b * G_ + g) * 5 + 2], ty2 = targets[(b * G_ + g) * 5 + 3];
    float aa = (tx2 - tx1) * (ty2 - ty1);
    float lv[5];
    int li[5];
#pragma unroll
    for (int k = 0; k < 5; ++k) { lv[k] = -INFINITY; li[k] = 0x7fffffff; }
    int base = ch * CHP_;
    for (int it = 0; it < CHP_ / 256; ++it) {
        int p = base + it * 256 + tid;
        int bi = best_idx[b * P_ + p];
        float bs = best_score[b * P_ + p];
        float v2;
        if (bi == g && bs > T1_) v2 = 0.f;  // kill (outface known true here)
        else {
            float4 pr = ((const float4*)priors)[p];
            float4 lc = ((const float4*)loc)[(size_t)b * P_ + p];
            v2 = iou_dec(decode_box(pr, lc), aa, tx1, ty1, tx2, ty2);
        }
        top5_insert(v2, p, lv, li);
    }
    __shared__ float sv[256 * 5];
    __shared__ int si[256 * 5];
#pragma unroll
    for (int k = 0; k < 5; ++k) { sv[tid * 5 + k] = lv[k]; si[tid * 5 + k] = li[k]; }
    __syncthreads();
    for (int str = 128; str > 0; str >>= 1) {
        if (tid < str) {
            int a = 0, c = 0;
            float ov[5];
            int oi[5];
#pragma unroll
            for (int k = 0; k < 5; ++k) {
                float va = sv[tid * 5 + a], vb = sv[(tid + str) * 5 + c];
                int ia = si[tid * 5 + a], ib = si[(tid + str) * 5 + c];
                bool ta = (va > vb) || (va == vb && ia < ib);
                ov[k] = ta ? va : vb;
                oi[k] = ta ? ia : ib;
                if (ta) a++; else c++;
            }
#pragma unroll
            for (int k = 0; k < 5; ++k) { sv[tid * 5 + k] = ov[k]; si[tid * 5 + k] = oi[k]; }
        }
        __syncthreads();
    }
    if (tid == 0) {
#pragma unroll
        for (int k = 0; k < 5; ++k) {
            cv5[((b * G_ + g) * CH_ + ch) * 5 + k] = sv[k];
            ci5[((b * G_ + g) * CH_ + ch) * 5 + k] = si[k];
        }
    }
}

// ---------------- kTail: merge top-5s, override resolution, comp losses, finalize ------
__global__ __launch_bounds__(256) void kTail(
    const float* __restrict__ loc, const float* __restrict__ conf,
    const float* __restrict__ priors, const float* __restrict__ targets,
    const Hdr* __restrict__ h,
    const double* __restrict__ fl_n_p, const double* __restrict__ sl_n_p,
    const float* __restrict__ cv5, const int* __restrict__ ci5,
    float* __restrict__ out) {
    int t = threadIdx.x, b = t >> 5, g = t & 31;
    __shared__ int selp[256][5];
    __shared__ int nS[256];
    __shared__ double aFlc[B_], aSlc[B_], aFln[B_], aSln[B_];
    __shared__ int aNp[B_], aCs[B_], aNpc[B_];

    int mc = h->match_cnt[t];
    int cm = h->c_match[t];
    int n = (mc < K_) ? min(cm, K_ - mc) : 0;
    nS[t] = n;

    // merge 8 chunk top-5 lists -> global top-5 for (b,g)  (only meaningful if n>0)
    float mv[5];
    int mi[5];
#pragma unroll
    for (int k = 0; k < 5; ++k) { mv[k] = -INFINITY; mi[k] = 0x7fffffff; }
    if (n > 0) {
        for (int ch = 0; ch < CH_; ++ch)
#pragma unroll
            for (int k = 0; k < 5; ++k)
                top5_insert(cv5[(t * CH_ + ch) * 5 + k], ci5[(t * CH_ + ch) * 5 + k], mv, mi);
    }
#pragma unroll
    for (int k = 0; k < 5; ++k) selp[t][k] = (k < n) ? mi[k] : -1;
    __syncthreads();

    // override resolution (scan over g ascending: later g wins) + comp losses
    double flc = 0.0, slc = 0.0;
    int alive = 0;
    float tg0 = targets[t * 5 + 0], tg1 = targets[t * 5 + 1];
    float tg2 = targets[t * 5 + 2], tg3 = targets[t * 5 + 3];
    float labf = targets[t * 5 + 4];
    int labi = (int)labf;
    for (int k = 0; k < n; ++k) {
        int p = mi[k];
        bool dead = false;
        for (int g2 = g + 1; g2 < G_; ++g2) {
            int q = b * G_ + g2;
            int n2 = nS[q];
            for (int k2 = 0; k2 < n2; ++k2)
                if (selp[q][k2] == p) dead = true;
        }
        if (!dead) {
            alive++;
            float4 pr = ((const float4*)priors)[p];
            float4 lc = ((const float4*)loc)[(size_t)b * P_ + p];
            float e0 = ((tg0 + tg2) * 0.5f - pr.x) / (V0_ * pr.z);
            float e1 = ((tg1 + tg3) * 0.5f - pr.y) / (V0_ * pr.w);
            float e2 = logf((tg2 - tg0) / pr.z) / V1_;
            float e3 = logf((tg3 - tg1) / pr.w) / V1_;
            slc += (double)sml1(lc.x, e0) + (double)sml1(lc.y, e1) +
                   (double)sml1(lc.z, e2) + (double)sml1(lc.w, e3);
            float2 cf = ((const float2*)conf)[(size_t)b * P_ + p];
            float cfs[2] = {cf.x, cf.y};
#pragma unroll
            for (int c = 0; c < C_; ++c) {
                float tt = (c == labi) ? labf : 0.f;  // labels[g] * one_hot
                flc += (double)focal_f(tt, cfs[c], mv[k]);
            }
        }
    }

    // per-b reductions within 32-thread subgroups (in-wave, no barriers)
    int rmc = mc, rn = n, ra = alive;
    double rf = flc, rs = slc;
    double pf = 0.0, ps = 0.0;  // normal-loss partials: slots [t*8, t*8+8) all belong to b
    for (int j = 0; j < 8; ++j) { pf += fl_n_p[t * 8 + j]; ps += sl_n_p[t * 8 + j]; }
    for (int off = 16; off > 0; off >>= 1) {
        rmc += __shfl_down(rmc, off, 32);
        rn += __shfl_down(rn, off, 32);
        ra += __shfl_down(ra, off, 32);
        rf += __shfl_down(rf, off, 32);
        rs += __shfl_down(rs, off, 32);
        pf += __shfl_down(pf, off, 32);
        ps += __shfl_down(ps, off, 32);
    }
    if (g == 0) {
        aNp[b] = rmc; aCs[b] = rn; aNpc[b] = ra;
        aFlc[b] = rf; aSlc[b] = rs; aFln[b] = pf; aSln[b] = ps;
    }
    __syncthreads();
    if (t == 0) {
        double sll = 0.0, scl = 0.0;
        for (int b2 = 0; b2 < B_; ++b2) {
            double l_loc = 0.0, l_cls = 0.0;
            int npos = aNp[b2];
            if (npos > 0) {
                l_cls += aFln[b2] / (double)npos;
                l_loc += aSln[b2] / (double)npos;
            }
            int csum = aCs[b2];
            if (csum > 0) {
                int npc = (aNpc[b2] > 1) ? aNpc[b2] : 1;
                l_loc += aSlc[b2] / (double)npc;
                l_cls += aFlc[b2] / (double)csum;
            }
            sll += l_loc;
            scl += l_cls;
        }
        out[0] = (float)(sll / B_);
        out[1] = (float)(scl / B_);
    }
}

extern "C" void kernel_launch(void* const* d_in, const int* in_sizes, int n_in,
                              void* d_out, int out_size, void* d_ws, size_t ws_size,
                              hipStream_t stream) {
    (void)in_sizes; (void)n_in; (void)out_size; (void)ws_size;
    const float* loc = (const float*)d_in[0];
    const float* conf = (const float*)d_in[1];
    const float* priors = (const float*)d_in[2];
    const float* targets = (const float*)d_in[3];
    float* out = (float*)d_out;
    char* ws = (char*)d_ws;
    Hdr* h = (Hdr*)ws;
    float* best_score = (float*)(ws + 8192);
    int* best_idx = (int*)(ws + 8192 + (size_t)B_ * P_ * 4);
    double* fl_n_p = (double*)(ws + 8192 + (size_t)B_ * P_ * 8);
    double* sl_n_p = fl_n_p + B_ * NBLK_;
    float* cv5 = (float*)(sl_n_p + B_ * NBLK_);
    int* ci5 = (int*)(cv5 + B_ * G_ * CH_ * 5);

    hipMemsetAsync(h, 0, sizeof(Hdr), stream);
    kA<<<dim3(NBLK_, B_), 256, 0, stream>>>(priors, targets, h, best_score, best_idx);
    kB<<<dim3(NBLK_, B_), 256, 0, stream>>>(loc, conf, priors, targets, h,
                                            best_score, best_idx, fl_n_p, sl_n_p);
    kD<<<dim3(G_ * CH_, B_), 256, 0, stream>>>(loc, priors, targets, h,
                                               best_score, best_idx, cv5, ci5);
    kTail<<<1, 256, 0, stream>>>(loc, conf, priors, targets, h, fl_n_p, sl_n_p, cv5, ci5, out);
}